// Round 5
// baseline (473.919 us; speedup 1.0000x reference)
//
#include <hip/hip_runtime.h>
#include <hip/hip_fp16.h>

// LinearAttention (phi = elu+1). B=8 S=4096 D=512 H=8 DH=64.
// Round 5: round 4 + (bisect suspect a) LDS-roundtrip epilogues in both GEMMs
// + attn_combine re-grid 512->1024 blocks (32-row tiles). Everything else
// round-4 verbatim. Split-bf16 3-product MFMA GEMMs, fused QKV dispatch.
// ws: [x_hi 32|x_lo 32|Wt_hi 2|Wt_lo 2|Qf 32|Kf 32|V 32|KVp 17|Ksp|KV|Ksum]

constexpr int Ss = 4096;
constexpr int Dd = 512;
constexpr int Hh = 8;
constexpr int Mtot = 8 * 4096;  // 32768
constexpr float EPSF = 1e-6f;

typedef short v8s __attribute__((ext_vector_type(8)));
typedef float v4f __attribute__((ext_vector_type(4)));

__device__ __forceinline__ short f2bf(float f) {  // RNE fp32 -> bf16
  unsigned u = __float_as_uint(f);
  u += 0x7fff + ((u >> 16) & 1);
  return (short)(u >> 16);
}
__device__ __forceinline__ float bf2f(short s) {
  return __uint_as_float(((unsigned)(unsigned short)s) << 16);
}
__device__ __forceinline__ void async_cp16(const void* g, void* l) {
  __builtin_amdgcn_global_load_lds((__attribute__((address_space(1))) void*)g,
                                   (__attribute__((address_space(3))) void*)l, 16, 0, 0);
}

// ---------- weight prep: W[512][512] -> Wt[n][k] bf16 hi/lo (4 matrices) ----------
__global__ __launch_bounds__(256) void prep_w(
    const float* __restrict__ W0, const float* __restrict__ W1,
    const float* __restrict__ W2, const float* __restrict__ W3,
    short* __restrict__ Th, short* __restrict__ Tl)
{
  const float* W = (blockIdx.z == 0) ? W0 : (blockIdx.z == 1) ? W1
                  : (blockIdx.z == 2) ? W2 : W3;
  short* th = Th + (size_t)blockIdx.z * 512 * 512;
  short* tl = Tl + (size_t)blockIdx.z * 512 * 512;
  __shared__ float tile[32][33];
  const int t = threadIdx.x;
  const int tx = t & 31, ty = t >> 5;  // 32 x 8
  const int k0 = blockIdx.x * 32, n0 = blockIdx.y * 32;
#pragma unroll
  for (int r = 0; r < 32; r += 8)
    tile[ty + r][tx] = W[(size_t)(k0 + ty + r) * 512 + n0 + tx];
  __syncthreads();
#pragma unroll
  for (int r = 0; r < 32; r += 8) {
    const float v = tile[tx][ty + r];  // = W[k0+tx][n0+ty+r]
    const short h = f2bf(v);
    const short l = f2bf(v - bf2f(h));
    th[(size_t)(n0 + ty + r) * 512 + k0 + tx] = h;
    tl[(size_t)(n0 + ty + r) * 512 + k0 + tx] = l;
  }
}

// ---------- x split: fp32 -> bf16 hi/lo ----------
__global__ __launch_bounds__(256) void split_x(
    const float* __restrict__ X, short* __restrict__ H, short* __restrict__ L, int n4)
{
  const int i = blockIdx.x * 256 + threadIdx.x;
  if (i >= n4) return;
  const float4 x = reinterpret_cast<const float4*>(X)[i];
  short4 h, l;
  h.x = f2bf(x.x); l.x = f2bf(x.x - bf2f(h.x));
  h.y = f2bf(x.y); l.y = f2bf(x.y - bf2f(h.y));
  h.z = f2bf(x.z); l.z = f2bf(x.z - bf2f(h.z));
  h.w = f2bf(x.w); l.w = f2bf(x.w - bf2f(h.w));
  reinterpret_cast<short4*>(H)[i] = h;
  reinterpret_cast<short4*>(L)[i] = l;
}

// ---------- fused QKV split-bf16 MFMA GEMM, LDS-roundtrip fp16 epilogue ------
// grid (Mtot/128, 12): y = mat*4 + colblock. phi for q,k.
__global__ __launch_bounds__(256) void gemm_qkv(
    const short* __restrict__ Ah, const short* __restrict__ Al,
    const short* __restrict__ Wth, const short* __restrict__ Wtl,
    const float* __restrict__ bq, const float* __restrict__ bk,
    const float* __restrict__ bv,
    __half* __restrict__ Qf, __half* __restrict__ Kf, __half* __restrict__ Vv)
{
  constexpr int K = 512;
  __shared__ __align__(16) short smem[16384];  // 32 KB
  short* As_h = smem;
  short* As_l = smem + 4096;
  short* Bs_h = smem + 8192;
  short* Bs_l = smem + 12288;

  const int mat = blockIdx.y >> 2;
  const int col0 = (blockIdx.y & 3) * 128;
  const int row0 = blockIdx.x * 128;
  const short* Bh = Wth + (size_t)mat * K * 512;
  const short* Bl = Wtl + (size_t)mat * K * 512;
  const float* bias = (mat == 0) ? bq : (mat == 1) ? bk : bv;
  __half* Co = (mat == 0) ? Qf : (mat == 1) ? Kf : Vv;
  const int act = (mat < 2);

  const int t = threadIdx.x;
  const int lane = t & 63;
  const int wv = t >> 6;
  const int wm = wv & 1, wn = wv >> 1;
  const int mr = lane & 15, kq = lane >> 4;

  v4f acc[4][4];
#pragma unroll
  for (int i = 0; i < 4; ++i)
#pragma unroll
    for (int j = 0; j < 4; ++j) acc[i][j] = (v4f){0.f, 0.f, 0.f, 0.f};

  const int srow = t >> 2;
  const int spq = t & 3;

  for (int k0 = 0; k0 < K; k0 += 32) {
#pragma unroll
    for (int c = 0; c < 2; ++c) {
      const int m = c * 64 + srow;
      const int q = spq ^ ((m >> 1) & 3);
      const size_t ga = (size_t)(row0 + m) * K + k0 + q * 8;
      const size_t gb = (size_t)(col0 + m) * K + k0 + q * 8;
      const int lo = c * 2048 + wv * 512;
      async_cp16(Ah + ga, As_h + lo);
      async_cp16(Al + ga, As_l + lo);
      async_cp16(Bh + gb, Bs_h + lo);
      async_cp16(Bl + gb, Bs_l + lo);
    }
    __syncthreads();

    v8s fah[4], fal[4], fbh[4], fbl[4];
#pragma unroll
    for (int i = 0; i < 4; ++i) {
      const int ma = wm * 64 + i * 16 + mr;
      const int pa = kq ^ ((ma >> 1) & 3);
      fah[i] = *reinterpret_cast<const v8s*>(&As_h[ma * 32 + pa * 8]);
      fal[i] = *reinterpret_cast<const v8s*>(&As_l[ma * 32 + pa * 8]);
      const int nb = wn * 64 + i * 16 + mr;
      const int pb = kq ^ ((nb >> 1) & 3);
      fbh[i] = *reinterpret_cast<const v8s*>(&Bs_h[nb * 32 + pb * 8]);
      fbl[i] = *reinterpret_cast<const v8s*>(&Bs_l[nb * 32 + pb * 8]);
    }
#pragma unroll
    for (int i = 0; i < 4; ++i)
#pragma unroll
      for (int j = 0; j < 4; ++j) {
        acc[i][j] = __builtin_amdgcn_mfma_f32_16x16x32_bf16(fah[i], fbh[j], acc[i][j], 0, 0, 0);
        acc[i][j] = __builtin_amdgcn_mfma_f32_16x16x32_bf16(fah[i], fbl[j], acc[i][j], 0, 0, 0);
        acc[i][j] = __builtin_amdgcn_mfma_f32_16x16x32_bf16(fal[i], fbh[j], acc[i][j], 0, 0, 0);
      }
    __syncthreads();
  }

  // epilogue: bias+phi -> LDS fp16 (XOR-swizzled cols) -> coalesced 16B stores
  // write: value (row=lr+r, logical col wn*64+j*16+mr) at physical col
  //        wn*64 + ((j^kq)<<4) + mr, kq = (row>>2)&3  -> 2-way banks (free)
  __half* hc = reinterpret_cast<__half*>(smem);  // [128][128]
#pragma unroll
  for (int j = 0; j < 4; ++j) {
    const float bz = bias[col0 + wn * 64 + j * 16 + mr];
#pragma unroll
    for (int i = 0; i < 4; ++i) {
      const int lr = wm * 64 + i * 16 + kq * 4;
      const int lc = wn * 64 + (((j * 16) ^ (kq << 4)) + mr);
#pragma unroll
      for (int r = 0; r < 4; ++r) {
        float v = acc[i][j][r] + bz;
        if (act) v = (v > 0.f) ? (v + 1.f) : __expf(v);
        hc[(lr + r) * 128 + lc] = __float2half(v);
      }
    }
  }
  __syncthreads();
  {
    const int r = t >> 1, half = (t & 1) * 64;
    const int sw = ((r >> 2) & 3) << 4;  // un-swizzle: logical = physical ^ sw
    __half* gout = Co + (size_t)(row0 + r) * 512 + col0 + half;
#pragma unroll
    for (int u = 0; u < 8; ++u) {
      const int pc = half + ((u * 8) ^ sw);
      *reinterpret_cast<v8s*>(gout + u * 8) =
          *reinterpret_cast<const v8s*>(&hc[r * 128 + pc]);
    }
  }
}

// ---------- final GEMM: out = attn @ Wo + bo, LDS-roundtrip fp32 epilogue ----
__global__ __launch_bounds__(256) void gemm_out(
    const short* __restrict__ Ah, const short* __restrict__ Al,
    const short* __restrict__ Bh, const short* __restrict__ Bl,
    const float* __restrict__ bias, float* __restrict__ Cf)
{
  constexpr int K = 512;
  __shared__ __align__(16) short smem[16384];
  short* As_h = smem;
  short* As_l = smem + 4096;
  short* Bs_h = smem + 8192;
  short* Bs_l = smem + 12288;

  const int col0 = blockIdx.y * 128;
  const int row0 = blockIdx.x * 128;
  const int t = threadIdx.x;
  const int lane = t & 63;
  const int wv = t >> 6;
  const int wm = wv & 1, wn = wv >> 1;
  const int mr = lane & 15, kq = lane >> 4;

  v4f acc[4][4];
#pragma unroll
  for (int i = 0; i < 4; ++i)
#pragma unroll
    for (int j = 0; j < 4; ++j) acc[i][j] = (v4f){0.f, 0.f, 0.f, 0.f};

  const int srow = t >> 2;
  const int spq = t & 3;

  for (int k0 = 0; k0 < K; k0 += 32) {
#pragma unroll
    for (int c = 0; c < 2; ++c) {
      const int m = c * 64 + srow;
      const int q = spq ^ ((m >> 1) & 3);
      const size_t ga = (size_t)(row0 + m) * K + k0 + q * 8;
      const size_t gb = (size_t)(col0 + m) * K + k0 + q * 8;
      const int lo = c * 2048 + wv * 512;
      async_cp16(Ah + ga, As_h + lo);
      async_cp16(Al + ga, As_l + lo);
      async_cp16(Bh + gb, Bs_h + lo);
      async_cp16(Bl + gb, Bs_l + lo);
    }
    __syncthreads();

    v8s fah[4], fal[4], fbh[4], fbl[4];
#pragma unroll
    for (int i = 0; i < 4; ++i) {
      const int ma = wm * 64 + i * 16 + mr;
      const int pa = kq ^ ((ma >> 1) & 3);
      fah[i] = *reinterpret_cast<const v8s*>(&As_h[ma * 32 + pa * 8]);
      fal[i] = *reinterpret_cast<const v8s*>(&As_l[ma * 32 + pa * 8]);
      const int nb = wn * 64 + i * 16 + mr;
      const int pb = kq ^ ((nb >> 1) & 3);
      fbh[i] = *reinterpret_cast<const v8s*>(&Bs_h[nb * 32 + pb * 8]);
      fbl[i] = *reinterpret_cast<const v8s*>(&Bs_l[nb * 32 + pb * 8]);
    }
#pragma unroll
    for (int i = 0; i < 4; ++i)
#pragma unroll
      for (int j = 0; j < 4; ++j) {
        acc[i][j] = __builtin_amdgcn_mfma_f32_16x16x32_bf16(fah[i], fbh[j], acc[i][j], 0, 0, 0);
        acc[i][j] = __builtin_amdgcn_mfma_f32_16x16x32_bf16(fah[i], fbl[j], acc[i][j], 0, 0, 0);
        acc[i][j] = __builtin_amdgcn_mfma_f32_16x16x32_bf16(fal[i], fbh[j], acc[i][j], 0, 0, 0);
      }
    __syncthreads();
  }

  // fp32 epilogue via LDS in two n-halves (128x64 f32 = 32 KB each)
  float* fc = reinterpret_cast<float*>(smem);
#pragma unroll
  for (int nh = 0; nh < 2; ++nh) {
    if (nh) __syncthreads();  // pass-0 reads complete before overwrite
    if (wn == nh) {
#pragma unroll
      for (int j = 0; j < 4; ++j) {
        const float bz = bias[col0 + nh * 64 + j * 16 + mr];
#pragma unroll
        for (int i = 0; i < 4; ++i) {
          const int lr = wm * 64 + i * 16 + kq * 4;
          const int lc = ((j * 16) ^ (kq << 4)) + mr;
#pragma unroll
          for (int r = 0; r < 4; ++r) fc[(lr + r) * 64 + lc] = acc[i][j][r] + bz;
        }
      }
    }
    __syncthreads();
    const int r = t >> 1, half = (t & 1) * 32;
    const int sw = ((r >> 2) & 3) << 4;
    float* gout = Cf + (size_t)(row0 + r) * 512 + col0 + nh * 64 + half;
#pragma unroll
    for (int u = 0; u < 8; ++u) {
      const int pc = (half + u * 4) ^ sw;
      *reinterpret_cast<float4*>(gout + u * 4) =
          *reinterpret_cast<const float4*>(&fc[r * 64 + pc]);
    }
  }
}

// ---------- KV stage 1 (round-2/4 verbatim): partial Kf^T@V and sum Kf -------
__global__ __launch_bounds__(256) void kv_stage1(
    const __half* __restrict__ Kf, const __half* __restrict__ V,
    float* __restrict__ KVp, float* __restrict__ Ksp)
{
  const int sc = blockIdx.x, bh = blockIdx.y;
  const int b = bh >> 3, h = bh & 7;
  __shared__ float Ks[64][68];
  __shared__ float Vs[64][68];
  const int tid = threadIdx.x;
  const int dx = (tid >> 4) * 4;
  const int mx = (tid & 15) * 4;
  float acc[4][4];
#pragma unroll
  for (int i = 0; i < 4; ++i)
#pragma unroll
    for (int j = 0; j < 4; ++j) acc[i][j] = 0.f;
  float ksum_acc = 0.f;
  const size_t base = (size_t)b * Ss * Dd + (size_t)h * 64;

  for (int s0 = sc * 256; s0 < sc * 256 + 256; s0 += 64) {
#pragma unroll
    for (int l = 0; l < 2; ++l) {
      const int idx = tid + l * 256;
      const int rr = idx >> 3, cq = idx & 7;
      const size_t g = base + (size_t)(s0 + rr) * Dd + cq * 8;
      const __half2* k2 = reinterpret_cast<const __half2*>(Kf + g);
      const __half2* v2 = reinterpret_cast<const __half2*>(V + g);
#pragma unroll
      for (int u = 0; u < 4; ++u) {
        const float2 kf = __half22float2(k2[u]);
        const float2 vf = __half22float2(v2[u]);
        Ks[rr][cq * 8 + u * 2] = kf.x; Ks[rr][cq * 8 + u * 2 + 1] = kf.y;
        Vs[rr][cq * 8 + u * 2] = vf.x; Vs[rr][cq * 8 + u * 2 + 1] = vf.y;
      }
    }
    __syncthreads();
#pragma unroll 4
    for (int s = 0; s < 64; ++s) {
      const float4 kd = *reinterpret_cast<const float4*>(&Ks[s][dx]);
      const float4 vm = *reinterpret_cast<const float4*>(&Vs[s][mx]);
      const float ka[4] = {kd.x, kd.y, kd.z, kd.w};
      const float va[4] = {vm.x, vm.y, vm.z, vm.w};
#pragma unroll
      for (int i = 0; i < 4; ++i)
#pragma unroll
        for (int j = 0; j < 4; ++j) acc[i][j] = fmaf(ka[i], va[j], acc[i][j]);
    }
    if (tid < 64) {
#pragma unroll 8
      for (int s = 0; s < 64; ++s) ksum_acc += Ks[s][tid];
    }
    __syncthreads();
  }

  const size_t pb = (size_t)(sc * 64 + bh);
#pragma unroll
  for (int i = 0; i < 4; ++i) {
    const float4 ov = {acc[i][0], acc[i][1], acc[i][2], acc[i][3]};
    *reinterpret_cast<float4*>(&KVp[(pb * 64 + dx + i) * 64 + mx]) = ov;
  }
  if (tid < 64) Ksp[pb * 64 + tid] = ksum_acc;
}

// ---------- KV stage 2 (round-2/4 verbatim): sum 16 partials ----------
__global__ __launch_bounds__(256) void kv_stage2(
    const float* __restrict__ KVp, const float* __restrict__ Ksp,
    float* __restrict__ KV, float* __restrict__ Ksum)
{
  const int bh = blockIdx.x, t = threadIdx.x;
  for (int e = t; e < 4096; e += 256) {
    float s = 0.f;
#pragma unroll
    for (int sc = 0; sc < 16; ++sc) s += KVp[((size_t)(sc * 64 + bh) << 12) + e];
    KV[(size_t)bh * 4096 + e] = s;
  }
  if (t < 64) {
    float s = 0.f;
#pragma unroll
    for (int sc = 0; sc < 16; ++sc) s += Ksp[(size_t)(sc * 64 + bh) * 64 + t];
    Ksum[bh * 64 + t] = s;
  }
}

// ---------- attn = Z * (Qf @ KV), 32-row tiles (1024 blocks) ----------
__global__ __launch_bounds__(256) void attn_combine(
    const __half* __restrict__ Qf, const float* __restrict__ KV,
    const float* __restrict__ Ksum, short* __restrict__ Oh, short* __restrict__ Ol)
{
  const int h = blockIdx.y;
  const int r0 = blockIdx.x * 32;  // 32-row tile
  const int b = r0 >> 12;
  const int bh = b * Hh + h;
  __shared__ float Qs[32][68];
  __shared__ float KVs[64][68];
  __shared__ float Ksums[64];
  __shared__ float Zs[32];
  const int tid = threadIdx.x;

  {  // Qs: 32 rows x 64 cols; one 16B fp16 load (8 vals) per thread
    const int rr = tid >> 3, cq = tid & 7;
    const __half2* q2 = reinterpret_cast<const __half2*>(
        Qf + (size_t)(r0 + rr) * Dd + h * 64 + cq * 8);
#pragma unroll
    for (int u = 0; u < 4; ++u) {
      const float2 qf = __half22float2(q2[u]);
      Qs[rr][cq * 8 + u * 2] = qf.x; Qs[rr][cq * 8 + u * 2 + 1] = qf.y;
    }
  }
#pragma unroll
  for (int l = 0; l < 4; ++l) {
    const int idx = tid + l * 256;
    const int rr = idx >> 4, cq = idx & 15;
    *reinterpret_cast<float4*>(&KVs[rr][cq * 4]) = *reinterpret_cast<const float4*>(
        &KV[(size_t)bh * 4096 + rr * 64 + cq * 4]);
  }
  if (tid < 64) Ksums[tid] = Ksum[bh * 64 + tid];
  __syncthreads();

  if (tid < 32) {
    float z = 0.f;
#pragma unroll 8
    for (int d = 0; d < 64; ++d) z = fmaf(Qs[tid][d], Ksums[d], z);
    Zs[tid] = 1.f / (z + EPSF);
  }
  __syncthreads();

  const int rx = (tid >> 4) * 2, mx = (tid & 15) * 4;
  float acc[2][4];
#pragma unroll
  for (int i = 0; i < 2; ++i)
#pragma unroll
    for (int j = 0; j < 4; ++j) acc[i][j] = 0.f;

#pragma unroll 4
  for (int d = 0; d < 64; ++d) {
    const float4 vm = *reinterpret_cast<const float4*>(&KVs[d][mx]);
    const float va[4] = {vm.x, vm.y, vm.z, vm.w};
#pragma unroll
    for (int i = 0; i < 2; ++i) {
      const float q = Qs[rx + i][d];
#pragma unroll
      for (int j = 0; j < 4; ++j) acc[i][j] = fmaf(q, va[j], acc[i][j]);
    }
  }

#pragma unroll
  for (int i = 0; i < 2; ++i) {
    const float z = Zs[rx + i];
    short4 hv, lv;
    float o;
    o = acc[i][0] * z; hv.x = f2bf(o); lv.x = f2bf(o - bf2f(hv.x));
    o = acc[i][1] * z; hv.y = f2bf(o); lv.y = f2bf(o - bf2f(hv.y));
    o = acc[i][2] * z; hv.z = f2bf(o); lv.z = f2bf(o - bf2f(hv.z));
    o = acc[i][3] * z; hv.w = f2bf(o); lv.w = f2bf(o - bf2f(hv.w));
    const size_t off = (size_t)(r0 + rx + i) * Dd + h * 64 + mx;
    *reinterpret_cast<short4*>(&Oh[off]) = hv;
    *reinterpret_cast<short4*>(&Ol[off]) = lv;
  }
}

extern "C" void kernel_launch(void* const* d_in, const int* in_sizes, int n_in,
                              void* d_out, int out_size, void* d_ws, size_t ws_size,
                              hipStream_t stream) {
  const float* x  = (const float*)d_in[0];
  const float* Wq = (const float*)d_in[1];
  const float* bq = (const float*)d_in[2];
  const float* Wk = (const float*)d_in[3];
  const float* bk = (const float*)d_in[4];
  const float* Wv = (const float*)d_in[5];
  const float* bv = (const float*)d_in[6];
  const float* Wo = (const float*)d_in[7];
  const float* bo = (const float*)d_in[8];
  float* out = (float*)d_out;

  char* ws = (char*)d_ws;
  const size_t MB = (size_t)1 << 20;
  short*  x_hi  = (short*)(ws);              // 32 MB (later: attn_hi)
  short*  x_lo  = (short*)(ws + 32 * MB);    // 32 MB (later: attn_lo)
  short*  Wt_hi = (short*)(ws + 64 * MB);    // 2 MB (4 x 512x512)
  short*  Wt_lo = (short*)(ws + 66 * MB);    // 2 MB
  __half* Qf    = (__half*)(ws + 68 * MB);   // 32 MB
  __half* Kf    = (__half*)(ws + 100 * MB);  // 32 MB
  __half* Vv    = (__half*)(ws + 132 * MB);  // 32 MB
  float*  KVp   = (float*)(ws + 164 * MB);   // 17 MB
  float*  Ksp   = (float*)(ws + 181 * MB);   // 256 KB
  float*  KV    = (float*)(ws + 182 * MB);   // 1 MB
  float*  Ksum  = (float*)(ws + 183 * MB);   // 16 KB
  short*  attn_hi = x_hi;
  short*  attn_lo = x_lo;
  const size_t WSTEP = (size_t)512 * 512;

  prep_w<<<dim3(16, 16, 4), 256, 0, stream>>>(Wq, Wk, Wv, Wo, Wt_hi, Wt_lo);
  split_x<<<Mtot * Dd / 4 / 256, 256, 0, stream>>>(x, x_hi, x_lo, Mtot * Dd / 4);

  gemm_qkv<<<dim3(Mtot / 128, 12), 256, 0, stream>>>(
      x_hi, x_lo, Wt_hi, Wt_lo, bq, bk, bv, Qf, Kf, Vv);

  kv_stage1<<<dim3(16, 64), 256, 0, stream>>>(Kf, Vv, KVp, Ksp);
  kv_stage2<<<64, 256, 0, stream>>>(KVp, Ksp, KV, Ksum);
  attn_combine<<<dim3(Mtot / 32, Hh), 256, 0, stream>>>(Qf, KV, Ksum, attn_hi, attn_lo);

  gemm_out<<<dim3(Mtot / 128, 4), 256, 0, stream>>>(
      attn_hi, attn_lo, Wt_hi + 3 * WSTEP, Wt_lo + 3 * WSTEP, bo, out);
}